// Round 1
// baseline (683.235 us; speedup 1.0000x reference)
//
#include <hip/hip_runtime.h>

#define N_NODES 100000
#define N_EDGES 1600000
#define N_GRAPHS 512
#define DIM 128
#define NCLS 10

// ---------------- edge prep ----------------

__global__ void k_init(int* __restrict__ deg, int* __restrict__ cursor, int n) {
    int i = blockIdx.x * 256 + threadIdx.x;
    if (i < n) { deg[i] = 0; cursor[i] = 0; }
}

__global__ void k_hist(const int* __restrict__ dst, int* __restrict__ deg, int E) {
    int e = blockIdx.x * 256 + threadIdx.x;
    if (e < E) atomicAdd(&deg[dst[e]], 1);
}

// Block-local exclusive scan of 2048 elements; also emits dinv = rsqrt(deg+1)
__global__ void k_scan1(const int* __restrict__ deg, int* __restrict__ rp,
                        int* __restrict__ partials, float* __restrict__ dinv, int n) {
    __shared__ int lds[256];
    int tid = threadIdx.x;
    int base = blockIdx.x * 2048 + tid * 8;
    int v[8], pre[8];
#pragma unroll
    for (int j = 0; j < 8; j++) {
        int idx = base + j;
        v[j] = (idx < n) ? deg[idx] : 0;
        if (idx < n) dinv[idx] = rsqrtf((float)(v[j] + 1)); // +1 self loop, deg>0 always
    }
    int s = 0;
#pragma unroll
    for (int j = 0; j < 8; j++) { pre[j] = s; s += v[j]; }
    lds[tid] = s;
    __syncthreads();
    for (int off = 1; off < 256; off <<= 1) {
        int t = (tid >= off) ? lds[tid - off] : 0;
        __syncthreads();
        lds[tid] += t;
        __syncthreads();
    }
    int excl = lds[tid] - s;
#pragma unroll
    for (int j = 0; j < 8; j++) {
        int idx = base + j;
        if (idx < n) rp[idx] = excl + pre[j];
    }
    if (tid == 255) partials[blockIdx.x] = lds[255];
}

__global__ void k_scan2(int* __restrict__ partials, int nb, int* __restrict__ rp, int n) {
    if (threadIdx.x == 0 && blockIdx.x == 0) {
        int run = 0;
        for (int i = 0; i < nb; i++) { int t = partials[i]; partials[i] = run; run += t; }
        rp[n] = run;
    }
}

__global__ void k_scan3(int* __restrict__ rp, const int* __restrict__ partials, int n) {
    int add = partials[blockIdx.x];
    int base = blockIdx.x * 2048;
#pragma unroll
    for (int j = 0; j < 8; j++) {
        int i = base + j * 256 + threadIdx.x;
        if (i < n) rp[i] += add;
    }
}

__global__ void k_scatter(const int* __restrict__ src, const int* __restrict__ dst,
                          const int* __restrict__ rp, int* __restrict__ cursor,
                          int* __restrict__ esrc, int E) {
    int e = blockIdx.x * 256 + threadIdx.x;
    if (e < E) {
        int d = dst[e];
        int p = atomicAdd(&cursor[d], 1);
        esrc[rp[d] + p] = src[e];
    }
}

// ---------------- GEMM: out[m] = dinv[m] * (A[m] @ W), M x 128 @ 128 x 128 ----------------
// Tile: 32 rows x 128 cols per block, K chunked by 32. 256 threads.
// Assumes M % 32 == 0 (100000 = 32*3125).

__global__ __launch_bounds__(256) void k_gemm_scaled(
    const float* __restrict__ A, const float* __restrict__ W,
    const float* __restrict__ dinv, float* __restrict__ out) {
    __shared__ float As[32 * 32];   // [row][k]
    __shared__ float Bs[32 * 128];  // [k][col]
    int tid = threadIdx.x;
    int tx = tid & 31;   // col group: cols tx*4 .. tx*4+3
    int ty = tid >> 5;   // rows ty + {0,8,16,24}
    int rowBase = blockIdx.x * 32;
    const float4* A4 = (const float4*)A;   // row stride 32 float4
    const float4* W4 = (const float4*)W;   // row stride 32 float4
    float4* As4 = (float4*)As;
    float4* Bs4 = (float4*)Bs;
    float acc[4][4];
#pragma unroll
    for (int r = 0; r < 4; r++)
#pragma unroll
        for (int c = 0; c < 4; c++) acc[r][c] = 0.f;

    for (int chunk = 0; chunk < 4; chunk++) {
        __syncthreads();
        {   // As: 32x32 = 256 float4, one per thread
            int row = tid >> 3, kc4 = tid & 7;
            As4[tid] = A4[(size_t)(rowBase + row) * 32 + chunk * 8 + kc4];
        }
#pragma unroll
        for (int j = 0; j < 4; j++) {  // Bs: 32x128 = 1024 float4
            int i = tid + j * 256;
            int krow = i >> 5, col4 = i & 31;
            Bs4[i] = W4[(size_t)(chunk * 32 + krow) * 32 + col4];
        }
        __syncthreads();
#pragma unroll
        for (int k = 0; k < 32; k++) {
            float4 b = Bs4[k * 32 + tx];
            float a0 = As[(ty + 0) * 32 + k];
            float a1 = As[(ty + 8) * 32 + k];
            float a2 = As[(ty + 16) * 32 + k];
            float a3 = As[(ty + 24) * 32 + k];
            acc[0][0] += a0 * b.x; acc[0][1] += a0 * b.y; acc[0][2] += a0 * b.z; acc[0][3] += a0 * b.w;
            acc[1][0] += a1 * b.x; acc[1][1] += a1 * b.y; acc[1][2] += a1 * b.z; acc[1][3] += a1 * b.w;
            acc[2][0] += a2 * b.x; acc[2][1] += a2 * b.y; acc[2][2] += a2 * b.z; acc[2][3] += a2 * b.w;
            acc[3][0] += a3 * b.x; acc[3][1] += a3 * b.y; acc[3][2] += a3 * b.z; acc[3][3] += a3 * b.w;
        }
    }
#pragma unroll
    for (int r = 0; r < 4; r++) {
        int row = rowBase + ty + r * 8;
        float s = dinv[row];
        float4 o = make_float4(acc[r][0] * s, acc[r][1] * s, acc[r][2] * s, acc[r][3] * s);
        ((float4*)out)[(size_t)row * 32 + tx] = o;
    }
}

// ---------------- CSR aggregation: out[d] = relu?(dinv[d]*(sum y[src] + y[d]) + bias) ----------------

__global__ __launch_bounds__(128) void k_agg(
    const float* __restrict__ y, const float* __restrict__ dinv,
    const int* __restrict__ rp, const int* __restrict__ esrc,
    const float* __restrict__ bias, float* __restrict__ out, int relu) {
    int node = blockIdx.x;
    int f = threadIdx.x;
    int beg = rp[node], end = rp[node + 1];
    float acc = y[(size_t)node * DIM + f];  // self loop (dinv[d]*y[d] factored outside)
    int j = beg;
    for (; j + 4 <= end; j += 4) {  // 4-way unroll for memory-level parallelism
        int s0 = esrc[j], s1 = esrc[j + 1], s2 = esrc[j + 2], s3 = esrc[j + 3];
        float v0 = y[(size_t)s0 * DIM + f];
        float v1 = y[(size_t)s1 * DIM + f];
        float v2 = y[(size_t)s2 * DIM + f];
        float v3 = y[(size_t)s3 * DIM + f];
        acc += v0; acc += v1; acc += v2; acc += v3;
    }
    for (; j < end; j++) acc += y[(size_t)esrc[j] * DIM + f];
    float o = dinv[node] * acc + bias[f];
    if (relu) o = fmaxf(o, 0.f);
    out[(size_t)node * DIM + f] = o;
}

// ---------------- mean pool (batch sorted -> binary search boundaries) ----------------

__global__ __launch_bounds__(128) void k_pool(
    const float* __restrict__ h, const int* __restrict__ batch,
    float* __restrict__ g, int n) {
    int gid = blockIdx.x;
    int f = threadIdx.x;
    int lo = 0, hi = n;
    while (lo < hi) { int mid = (lo + hi) >> 1; if (batch[mid] < gid) lo = mid + 1; else hi = mid; }
    int start = lo;
    hi = n;
    while (lo < hi) { int mid = (lo + hi) >> 1; if (batch[mid] < gid + 1) lo = mid + 1; else hi = mid; }
    int end = lo;
    float acc = 0.f;
    for (int i = start; i < end; i++) acc += h[(size_t)i * DIM + f];
    int cnt = end - start;
    g[gid * DIM + f] = acc / (float)(cnt > 0 ? cnt : 1);
}

// ---------------- classifier head: out = g @ Wc + bc ----------------

__global__ __launch_bounds__(128) void k_final(
    const float* __restrict__ g, const float* __restrict__ Wc,
    const float* __restrict__ bc, float* __restrict__ out) {
    __shared__ float row[DIM];
    int gid = blockIdx.x;
    row[threadIdx.x] = g[gid * DIM + threadIdx.x];
    __syncthreads();
    int c = threadIdx.x;
    if (c < NCLS) {
        float acc = bc[c];
#pragma unroll 16
        for (int k = 0; k < DIM; k++) acc += row[k] * Wc[k * NCLS + c];
        out[gid * NCLS + c] = acc;
    }
}

extern "C" void kernel_launch(void* const* d_in, const int* in_sizes, int n_in,
                              void* d_out, int out_size, void* d_ws, size_t ws_size,
                              hipStream_t stream) {
    const float* x    = (const float*)d_in[0];
    const int*   ei   = (const int*)d_in[1];   // [2][E] int32
    const int*   batch= (const int*)d_in[2];
    const float* W1   = (const float*)d_in[3];
    const float* b1   = (const float*)d_in[4];
    const float* W2   = (const float*)d_in[5];
    const float* b2   = (const float*)d_in[6];
    const float* Wc   = (const float*)d_in[7];
    const float* bc   = (const float*)d_in[8];
    float* out = (float*)d_out;
    const int N = N_NODES, E = N_EDGES;
    const int* src = ei;
    const int* dst = ei + E;

    char* ws = (char*)d_ws;
    size_t off = 0;
    auto carve = [&](size_t bytes) -> void* {
        void* p = ws + off;
        off = (off + bytes + 255) & ~(size_t)255;
        return p;
    };
    int*   deg      = (int*)  carve((size_t)N * 4);
    int*   cursor   = (int*)  carve((size_t)N * 4);
    int*   rp       = (int*)  carve((size_t)(N + 1) * 4);
    int*   partials = (int*)  carve(64 * 4);
    float* dinv     = (float*)carve((size_t)N * 4);
    int*   esrc     = (int*)  carve((size_t)E * 4);
    float* bufA     = (float*)carve((size_t)N * DIM * 4);
    float* bufB     = (float*)carve((size_t)N * DIM * 4);
    float* g        = (float*)carve((size_t)N_GRAPHS * DIM * 4);
    (void)ws_size; (void)n_in; (void)in_sizes; (void)out_size;

    int nb = (N + 2047) / 2048;  // 49
    hipLaunchKernelGGL(k_init,    dim3((N + 255) / 256), dim3(256), 0, stream, deg, cursor, N);
    hipLaunchKernelGGL(k_hist,    dim3((E + 255) / 256), dim3(256), 0, stream, dst, deg, E);
    hipLaunchKernelGGL(k_scan1,   dim3(nb),  dim3(256), 0, stream, deg, rp, partials, dinv, N);
    hipLaunchKernelGGL(k_scan2,   dim3(1),   dim3(64),  0, stream, partials, nb, rp, N);
    hipLaunchKernelGGL(k_scan3,   dim3(nb),  dim3(256), 0, stream, rp, partials, N);
    hipLaunchKernelGGL(k_scatter, dim3((E + 255) / 256), dim3(256), 0, stream, src, dst, rp, cursor, esrc, E);

    // conv1: y = dinv*(x@W1); h1 = relu(dinv*agg(y) + b1)
    hipLaunchKernelGGL(k_gemm_scaled, dim3(N / 32), dim3(256), 0, stream, x, W1, dinv, bufA);
    hipLaunchKernelGGL(k_agg,         dim3(N),      dim3(128), 0, stream, bufA, dinv, rp, esrc, b1, bufB, 1);
    // conv2
    hipLaunchKernelGGL(k_gemm_scaled, dim3(N / 32), dim3(256), 0, stream, bufB, W2, dinv, bufA);
    hipLaunchKernelGGL(k_agg,         dim3(N),      dim3(128), 0, stream, bufA, dinv, rp, esrc, b2, bufB, 0);
    // pool + head
    hipLaunchKernelGGL(k_pool,  dim3(N_GRAPHS), dim3(128), 0, stream, bufB, batch, g, N);
    hipLaunchKernelGGL(k_final, dim3(N_GRAPHS), dim3(128), 0, stream, g, Wc, bc, out);
}

// Round 2
// 546.015 us; speedup vs baseline: 1.2513x; 1.2513x over previous
//
#include <hip/hip_runtime.h>

#define N_NODES 100000
#define N_EDGES 1600000
#define N_GRAPHS 512
#define DIM 128
#define NCLS 10
#define NBKT 98           // ceil(100000 / 1024) buckets of 1024 nodes

static __device__ __forceinline__ unsigned short f2bf(float f) {
    unsigned u = __float_as_uint(f);
    unsigned r = (u + 0x7FFF + ((u >> 16) & 1)) >> 16;  // RNE
    return (unsigned short)r;
}
static __device__ __forceinline__ float bf2f(unsigned u) {
    return __uint_as_float(u << 16);
}

// ---------------- edge prep ----------------

__global__ void k_init(int* __restrict__ deg, int n) {
    int i = blockIdx.x * 256 + threadIdx.x;
    if (i < n) deg[i] = 0;
}

__global__ void k_hist(const int* __restrict__ dst, int* __restrict__ deg, int E) {
    int e = blockIdx.x * 256 + threadIdx.x;
    if (e < E) atomicAdd(&deg[dst[e]], 1);
}

// Block-local exclusive scan of 2048 elements; also emits dinv = rsqrt(deg+1)
__global__ void k_scan1(const int* __restrict__ deg, int* __restrict__ rp,
                        int* __restrict__ partials, float* __restrict__ dinv, int n) {
    __shared__ int lds[256];
    int tid = threadIdx.x;
    int base = blockIdx.x * 2048 + tid * 8;
    int v[8], pre[8];
#pragma unroll
    for (int j = 0; j < 8; j++) {
        int idx = base + j;
        v[j] = (idx < n) ? deg[idx] : 0;
        if (idx < n) dinv[idx] = rsqrtf((float)(v[j] + 1)); // +1 self loop
    }
    int s = 0;
#pragma unroll
    for (int j = 0; j < 8; j++) { pre[j] = s; s += v[j]; }
    lds[tid] = s;
    __syncthreads();
    for (int off = 1; off < 256; off <<= 1) {
        int t = (tid >= off) ? lds[tid - off] : 0;
        __syncthreads();
        lds[tid] += t;
        __syncthreads();
    }
    int excl = lds[tid] - s;
#pragma unroll
    for (int j = 0; j < 8; j++) {
        int idx = base + j;
        if (idx < n) rp[idx] = excl + pre[j];
    }
    if (tid == 255) partials[blockIdx.x] = lds[255];
}

__global__ void k_scan2(int* __restrict__ partials, int nb, int* __restrict__ rp, int n) {
    if (threadIdx.x == 0 && blockIdx.x == 0) {
        int run = 0;
        for (int i = 0; i < nb; i++) { int t = partials[i]; partials[i] = run; run += t; }
        rp[n] = run;
    }
}

// adds block prefix; also emits bucket cursors bcur[b] = rp[b*1024]
__global__ void k_scan3(int* __restrict__ rp, const int* __restrict__ partials,
                        int* __restrict__ bcur, int n) {
    int add = partials[blockIdx.x];
    int base = blockIdx.x * 2048;
#pragma unroll
    for (int j = 0; j < 8; j++) {
        int i = base + j * 256 + threadIdx.x;
        if (i < n) {
            int v = rp[i] + add;
            rp[i] = v;
            if ((i & 1023) == 0) bcur[i >> 10] = v;
        }
    }
}

// Pass A: partition edges into NBKT buckets of 1024 dst-nodes, packed
// (dstlocal<<17 | src). Block-local histogram -> one global atomic per
// bucket per block -> dense appends (write-locality fix vs 4B random scatter).
__global__ __launch_bounds__(256) void k_bucket(
    const int* __restrict__ src, const int* __restrict__ dst,
    int* __restrict__ bcur, unsigned* __restrict__ bpack, int E) {
    __shared__ int cnt[NBKT];
    __shared__ int base[NBKT];
    int tid = threadIdx.x;
    if (tid < NBKT) cnt[tid] = 0;
    __syncthreads();
    int e0 = blockIdx.x * 4096 + tid;
    unsigned pk[16]; short bk[16];
#pragma unroll
    for (int j = 0; j < 16; j++) {
        int e = e0 + j * 256;
        if (e < E) {
            int s = src[e], d = dst[e];
            bk[j] = (short)(d >> 10);
            pk[j] = ((unsigned)(d & 1023) << 17) | (unsigned)s;
            atomicAdd(&cnt[bk[j]], 1);
        } else bk[j] = -1;
    }
    __syncthreads();
    if (tid < NBKT) {
        int c = cnt[tid];
        base[tid] = c ? atomicAdd(&bcur[tid], c) : 0;
        cnt[tid] = 0;
    }
    __syncthreads();
#pragma unroll
    for (int j = 0; j < 16; j++) {
        if (bk[j] >= 0) {
            int p = base[bk[j]] + atomicAdd(&cnt[bk[j]], 1);
            bpack[p] = pk[j];
        }
    }
}

// Pass B: per-bucket scatter to final CSR position via LDS cursors.
// Final esrc writes land in ONE contiguous ~64KB region per workgroup.
__global__ __launch_bounds__(256) void k_bsort(
    const unsigned* __restrict__ bpack, const int* __restrict__ rp,
    int* __restrict__ esrc, int N) {
    __shared__ int cur[1024];
    int b = blockIdx.x;
    int n0 = b << 10;
    int tid = threadIdx.x;
    for (int i = tid; i < 1024; i += 256) {
        int node = n0 + i;
        cur[i] = (node < N) ? rp[node] : 0;
    }
    __syncthreads();
    int beg = rp[n0];
    int endNode = (n0 + 1024 < N) ? (n0 + 1024) : N;
    int end = rp[endNode];
    for (int j = beg + tid; j < end; j += 256) {
        unsigned pk = bpack[j];
        int p = atomicAdd(&cur[pk >> 17], 1);
        esrc[p] = (int)(pk & 0x1FFFF);
    }
}

// ---------------- GEMM: ybf[m] = bf16( dinv[m] * (A[m] @ W) ) ----------------
// 32 rows x 128 cols per block, K chunked by 32, 256 threads. M % 32 == 0.

__global__ __launch_bounds__(256) void k_gemm_scaled(
    const float* __restrict__ A, const float* __restrict__ W,
    const float* __restrict__ dinv, unsigned short* __restrict__ outbf) {
    __shared__ float As[32 * 32];   // [row][k]
    __shared__ float Bs[32 * 128];  // [k][col]
    int tid = threadIdx.x;
    int tx = tid & 31;   // cols tx*4 .. tx*4+3
    int ty = tid >> 5;   // rows ty + {0,8,16,24}
    int rowBase = blockIdx.x * 32;
    const float4* A4 = (const float4*)A;
    const float4* W4 = (const float4*)W;
    float4* As4 = (float4*)As;
    float4* Bs4 = (float4*)Bs;
    float acc[4][4];
#pragma unroll
    for (int r = 0; r < 4; r++)
#pragma unroll
        for (int c = 0; c < 4; c++) acc[r][c] = 0.f;

    for (int chunk = 0; chunk < 4; chunk++) {
        __syncthreads();
        {
            int row = tid >> 3, kc4 = tid & 7;
            As4[tid] = A4[(size_t)(rowBase + row) * 32 + chunk * 8 + kc4];
        }
#pragma unroll
        for (int j = 0; j < 4; j++) {
            int i = tid + j * 256;
            int krow = i >> 5, col4 = i & 31;
            Bs4[i] = W4[(size_t)(chunk * 32 + krow) * 32 + col4];
        }
        __syncthreads();
#pragma unroll
        for (int k = 0; k < 32; k++) {
            float4 b = Bs4[k * 32 + tx];
            float a0 = As[(ty + 0) * 32 + k];
            float a1 = As[(ty + 8) * 32 + k];
            float a2 = As[(ty + 16) * 32 + k];
            float a3 = As[(ty + 24) * 32 + k];
            acc[0][0] += a0 * b.x; acc[0][1] += a0 * b.y; acc[0][2] += a0 * b.z; acc[0][3] += a0 * b.w;
            acc[1][0] += a1 * b.x; acc[1][1] += a1 * b.y; acc[1][2] += a1 * b.z; acc[1][3] += a1 * b.w;
            acc[2][0] += a2 * b.x; acc[2][1] += a2 * b.y; acc[2][2] += a2 * b.z; acc[2][3] += a2 * b.w;
            acc[3][0] += a3 * b.x; acc[3][1] += a3 * b.y; acc[3][2] += a3 * b.z; acc[3][3] += a3 * b.w;
        }
    }
#pragma unroll
    for (int r = 0; r < 4; r++) {
        int row = rowBase + ty + r * 8;
        float s = dinv[row];
        unsigned short q0 = f2bf(acc[r][0] * s), q1 = f2bf(acc[r][1] * s);
        unsigned short q2 = f2bf(acc[r][2] * s), q3 = f2bf(acc[r][3] * s);
        uint2 o = make_uint2((unsigned)q0 | ((unsigned)q1 << 16),
                             (unsigned)q2 | ((unsigned)q3 << 16));
        ((uint2*)outbf)[(size_t)row * 32 + tx] = o;
    }
}

// ---------------- CSR aggregation (bf16 gather, wave-per-node) ----------------
// out[d] = relu?( dinv[d]*(sum_{s in N(d)} y[s] + y[d]) + bias )
// 64 lanes x 4B (2 bf16) = one 256B gather per edge per wave.

__global__ __launch_bounds__(256) void k_agg(
    const unsigned short* __restrict__ y, const float* __restrict__ dinv,
    const int* __restrict__ rp, const int* __restrict__ esrc,
    const float* __restrict__ bias, float* __restrict__ out, int relu, int N) {
    int wave = threadIdx.x >> 6;
    int lane = threadIdx.x & 63;
    int node = blockIdx.x * 4 + wave;
    if (node >= N) return;
    const unsigned* y2 = (const unsigned*)y;   // 2 bf16 per u32, row stride 64
    unsigned vs = y2[(size_t)node * 64 + lane];       // self loop
    float a0 = bf2f(vs & 0xFFFF), a1 = bf2f(vs >> 16);
    int beg = rp[node], end = rp[node + 1];
    int j = beg;
    for (; j + 4 <= end; j += 4) {
        int s0 = esrc[j], s1 = esrc[j + 1], s2 = esrc[j + 2], s3 = esrc[j + 3];
        unsigned v0 = y2[(size_t)s0 * 64 + lane];
        unsigned v1 = y2[(size_t)s1 * 64 + lane];
        unsigned v2 = y2[(size_t)s2 * 64 + lane];
        unsigned v3 = y2[(size_t)s3 * 64 + lane];
        a0 += bf2f(v0 & 0xFFFF); a1 += bf2f(v0 >> 16);
        a0 += bf2f(v1 & 0xFFFF); a1 += bf2f(v1 >> 16);
        a0 += bf2f(v2 & 0xFFFF); a1 += bf2f(v2 >> 16);
        a0 += bf2f(v3 & 0xFFFF); a1 += bf2f(v3 >> 16);
    }
    for (; j < end; j++) {
        unsigned v = y2[(size_t)esrc[j] * 64 + lane];
        a0 += bf2f(v & 0xFFFF); a1 += bf2f(v >> 16);
    }
    float s = dinv[node];
    float o0 = s * a0 + bias[lane * 2];
    float o1 = s * a1 + bias[lane * 2 + 1];
    if (relu) { o0 = fmaxf(o0, 0.f); o1 = fmaxf(o1, 0.f); }
    ((float2*)out)[(size_t)node * 64 + lane] = make_float2(o0, o1);
}

// ---------------- mean pool (batch sorted -> binary search boundaries) ----------------

__global__ __launch_bounds__(128) void k_pool(
    const float* __restrict__ h, const int* __restrict__ batch,
    float* __restrict__ g, int n) {
    int gid = blockIdx.x;
    int f = threadIdx.x;
    int lo = 0, hi = n;
    while (lo < hi) { int mid = (lo + hi) >> 1; if (batch[mid] < gid) lo = mid + 1; else hi = mid; }
    int start = lo;
    hi = n;
    while (lo < hi) { int mid = (lo + hi) >> 1; if (batch[mid] < gid + 1) lo = mid + 1; else hi = mid; }
    int end = lo;
    float acc = 0.f;
    for (int i = start; i < end; i++) acc += h[(size_t)i * DIM + f];
    int cnt = end - start;
    g[gid * DIM + f] = acc / (float)(cnt > 0 ? cnt : 1);
}

// ---------------- classifier head: out = g @ Wc + bc ----------------

__global__ __launch_bounds__(128) void k_final(
    const float* __restrict__ g, const float* __restrict__ Wc,
    const float* __restrict__ bc, float* __restrict__ out) {
    __shared__ float row[DIM];
    int gid = blockIdx.x;
    row[threadIdx.x] = g[gid * DIM + threadIdx.x];
    __syncthreads();
    int c = threadIdx.x;
    if (c < NCLS) {
        float acc = bc[c];
#pragma unroll 16
        for (int k = 0; k < DIM; k++) acc += row[k] * Wc[k * NCLS + c];
        out[gid * NCLS + c] = acc;
    }
}

extern "C" void kernel_launch(void* const* d_in, const int* in_sizes, int n_in,
                              void* d_out, int out_size, void* d_ws, size_t ws_size,
                              hipStream_t stream) {
    const float* x    = (const float*)d_in[0];
    const int*   ei   = (const int*)d_in[1];
    const int*   batch= (const int*)d_in[2];
    const float* W1   = (const float*)d_in[3];
    const float* b1   = (const float*)d_in[4];
    const float* W2   = (const float*)d_in[5];
    const float* b2   = (const float*)d_in[6];
    const float* Wc   = (const float*)d_in[7];
    const float* bc   = (const float*)d_in[8];
    float* out = (float*)d_out;
    const int N = N_NODES, E = N_EDGES;
    const int* src = ei;
    const int* dst = ei + E;

    char* ws = (char*)d_ws;
    size_t off = 0;
    auto carve = [&](size_t bytes) -> void* {
        void* p = ws + off;
        off = (off + bytes + 255) & ~(size_t)255;
        return p;
    };
    int*      deg      = (int*)     carve((size_t)N * 4);
    int*      rp       = (int*)     carve((size_t)(N + 1) * 4);
    int*      partials = (int*)     carve(64 * 4);
    float*    dinv     = (float*)   carve((size_t)N * 4);
    int*      bcur     = (int*)     carve(NBKT * 4);
    unsigned* bpack    = (unsigned*)carve((size_t)E * 4);
    int*      esrc     = (int*)     carve((size_t)E * 4);
    unsigned short* bufY = (unsigned short*)carve((size_t)N * DIM * 2);
    float*    bufH     = (float*)   carve((size_t)N * DIM * 4);
    float*    g        = (float*)   carve((size_t)N_GRAPHS * DIM * 4);
    (void)ws_size; (void)n_in; (void)in_sizes; (void)out_size;

    int nb = (N + 2047) / 2048;  // 49
    hipLaunchKernelGGL(k_init,   dim3((N + 255) / 256), dim3(256), 0, stream, deg, N);
    hipLaunchKernelGGL(k_hist,   dim3((E + 255) / 256), dim3(256), 0, stream, dst, deg, E);
    hipLaunchKernelGGL(k_scan1,  dim3(nb), dim3(256), 0, stream, deg, rp, partials, dinv, N);
    hipLaunchKernelGGL(k_scan2,  dim3(1),  dim3(64),  0, stream, partials, nb, rp, N);
    hipLaunchKernelGGL(k_scan3,  dim3(nb), dim3(256), 0, stream, rp, partials, bcur, N);
    hipLaunchKernelGGL(k_bucket, dim3((E + 4095) / 4096), dim3(256), 0, stream, src, dst, bcur, bpack, E);
    hipLaunchKernelGGL(k_bsort,  dim3(NBKT), dim3(256), 0, stream, bpack, rp, esrc, N);

    // conv1: y = bf16(dinv*(x@W1)); h = relu(dinv*agg(y) + b1)
    hipLaunchKernelGGL(k_gemm_scaled, dim3(N / 32), dim3(256), 0, stream, x, W1, dinv, bufY);
    hipLaunchKernelGGL(k_agg, dim3((N + 3) / 4), dim3(256), 0, stream, bufY, dinv, rp, esrc, b1, bufH, 1, N);
    // conv2
    hipLaunchKernelGGL(k_gemm_scaled, dim3(N / 32), dim3(256), 0, stream, bufH, W2, dinv, bufY);
    hipLaunchKernelGGL(k_agg, dim3((N + 3) / 4), dim3(256), 0, stream, bufY, dinv, rp, esrc, b2, bufH, 0, N);
    // pool + head
    hipLaunchKernelGGL(k_pool,  dim3(N_GRAPHS), dim3(128), 0, stream, bufH, batch, g, N);
    hipLaunchKernelGGL(k_final, dim3(N_GRAPHS), dim3(128), 0, stream, g, Wc, bc, out);
}

// Round 3
// 519.486 us; speedup vs baseline: 1.3152x; 1.0511x over previous
//
#include <hip/hip_runtime.h>

#define N_NODES 100000
#define N_EDGES 1600000
#define N_GRAPHS 512
#define DIM 128
#define NCLS 10
#define NBKT 98           // ceil(100000 / 1024) buckets of 1024 nodes

typedef __attribute__((ext_vector_type(8))) short short8;
typedef __attribute__((ext_vector_type(4))) float f32x4;

static __device__ __forceinline__ unsigned short f2bf(float f) {
    unsigned u = __float_as_uint(f);
    unsigned r = (u + 0x7FFF + ((u >> 16) & 1)) >> 16;  // RNE
    return (unsigned short)r;
}
static __device__ __forceinline__ float bf2f(unsigned u) {
    return __uint_as_float(u << 16);
}

// ---------------- edge prep ----------------

__global__ void k_init(int* __restrict__ deg, int n) {
    int i = blockIdx.x * 256 + threadIdx.x;
    if (i < n) deg[i] = 0;
}

__global__ void k_hist(const int* __restrict__ dst, int* __restrict__ deg, int E) {
    int e = blockIdx.x * 256 + threadIdx.x;
    if (e < E) atomicAdd(&deg[dst[e]], 1);
}

// Block-local exclusive scan of 2048 elements; also emits dinv = rsqrt(deg+1)
__global__ void k_scan1(const int* __restrict__ deg, int* __restrict__ rp,
                        int* __restrict__ partials, float* __restrict__ dinv, int n) {
    __shared__ int lds[256];
    int tid = threadIdx.x;
    int base = blockIdx.x * 2048 + tid * 8;
    int v[8], pre[8];
#pragma unroll
    for (int j = 0; j < 8; j++) {
        int idx = base + j;
        v[j] = (idx < n) ? deg[idx] : 0;
        if (idx < n) dinv[idx] = rsqrtf((float)(v[j] + 1)); // +1 self loop
    }
    int s = 0;
#pragma unroll
    for (int j = 0; j < 8; j++) { pre[j] = s; s += v[j]; }
    lds[tid] = s;
    __syncthreads();
    for (int off = 1; off < 256; off <<= 1) {
        int t = (tid >= off) ? lds[tid - off] : 0;
        __syncthreads();
        lds[tid] += t;
        __syncthreads();
    }
    int excl = lds[tid] - s;
#pragma unroll
    for (int j = 0; j < 8; j++) {
        int idx = base + j;
        if (idx < n) rp[idx] = excl + pre[j];
    }
    if (tid == 255) partials[blockIdx.x] = lds[255];
}

__global__ void k_scan2(int* __restrict__ partials, int nb, int* __restrict__ rp, int n) {
    if (threadIdx.x == 0 && blockIdx.x == 0) {
        int run = 0;
        for (int i = 0; i < nb; i++) { int t = partials[i]; partials[i] = run; run += t; }
        rp[n] = run;
    }
}

__global__ void k_scan3(int* __restrict__ rp, const int* __restrict__ partials,
                        int* __restrict__ bcur, int n) {
    int add = partials[blockIdx.x];
    int base = blockIdx.x * 2048;
#pragma unroll
    for (int j = 0; j < 8; j++) {
        int i = base + j * 256 + threadIdx.x;
        if (i < n) {
            int v = rp[i] + add;
            rp[i] = v;
            if ((i & 1023) == 0) bcur[i >> 10] = v;
        }
    }
}

// Pass A: partition edges into NBKT buckets of 1024 dst-nodes, packed (dstlocal<<17 | src).
__global__ __launch_bounds__(256) void k_bucket(
    const int* __restrict__ src, const int* __restrict__ dst,
    int* __restrict__ bcur, unsigned* __restrict__ bpack, int E) {
    __shared__ int cnt[NBKT];
    __shared__ int base[NBKT];
    int tid = threadIdx.x;
    if (tid < NBKT) cnt[tid] = 0;
    __syncthreads();
    int e0 = blockIdx.x * 4096 + tid;
    unsigned pk[16]; short bk[16];
#pragma unroll
    for (int j = 0; j < 16; j++) {
        int e = e0 + j * 256;
        if (e < E) {
            int s = src[e], d = dst[e];
            bk[j] = (short)(d >> 10);
            pk[j] = ((unsigned)(d & 1023) << 17) | (unsigned)s;
            atomicAdd(&cnt[bk[j]], 1);
        } else bk[j] = -1;
    }
    __syncthreads();
    if (tid < NBKT) {
        int c = cnt[tid];
        base[tid] = c ? atomicAdd(&bcur[tid], c) : 0;
        cnt[tid] = 0;
    }
    __syncthreads();
#pragma unroll
    for (int j = 0; j < 16; j++) {
        if (bk[j] >= 0) {
            int p = base[bk[j]] + atomicAdd(&cnt[bk[j]], 1);
            bpack[p] = pk[j];
        }
    }
}

// Pass B: per-bucket scatter to final CSR position via LDS cursors.
__global__ __launch_bounds__(256) void k_bsort(
    const unsigned* __restrict__ bpack, const int* __restrict__ rp,
    int* __restrict__ esrc, int N) {
    __shared__ int cur[1024];
    int b = blockIdx.x;
    int n0 = b << 10;
    int tid = threadIdx.x;
    for (int i = tid; i < 1024; i += 256) {
        int node = n0 + i;
        cur[i] = (node < N) ? rp[node] : 0;
    }
    __syncthreads();
    int beg = rp[n0];
    int endNode = (n0 + 1024 < N) ? (n0 + 1024) : N;
    int end = rp[endNode];
    for (int j = beg + tid; j < end; j += 256) {
        unsigned pk = bpack[j];
        int p = atomicAdd(&cur[pk >> 17], 1);
        esrc[p] = (int)(pk & 0x1FFFF);
    }
}

// ---------------- W fragment prep: swizzle W [128][128] fp32 -> MFMA B-layout bf16 hi/lo ----------------
// wfrag[hi: t<16384][lo: +16384], t = ((kit*8+nt)*64+lane)*8+j
// B element: k = kit*32 + (lane>>4)*8 + j, n = nt*16 + (lane&15)

__global__ void k_wprep(const float* __restrict__ W, unsigned short* __restrict__ wfrag) {
    int t = blockIdx.x * 256 + threadIdx.x;   // 0..16383
    int j = t & 7, lane = (t >> 3) & 63, nt = (t >> 9) & 7, kit = t >> 12;
    int k = kit * 32 + (lane >> 4) * 8 + j;
    int n = nt * 16 + (lane & 15);
    float v = W[k * 128 + n];
    unsigned short h = f2bf(v);
    wfrag[t] = h;
    wfrag[16384 + t] = f2bf(v - bf2f(h));
}

// ---------------- MFMA GEMM: ybf[m] = bf16( dinv[m] * (A[m] @ W) ) ----------------
// fp32-accurate via hi/lo split: A@W = Ahi@Whi + Ahi@Wlo + Alo@Whi.
// Block = 256 thr = 4 waves, 64 rows; wave strip = 16 rows x 128 cols = 8 C-tiles.
// A frags loaded straight from global (128B/row segments); W frags from global (64KB, L2-hot).

__global__ __launch_bounds__(256) void k_gemm_mfma(
    const float* __restrict__ A, const unsigned short* __restrict__ wfrag,
    const float* __restrict__ dinv, unsigned short* __restrict__ ybf, int M) {
    __shared__ unsigned short scr[4 * 16 * 136];   // per-wave 16x128 strip, stride 136 (16B-aligned rows)
    int tid = threadIdx.x;
    int wave = tid >> 6, lane = tid & 63;
    int m = lane & 15, quad = lane >> 4;
    int rowBase = blockIdx.x * 64 + wave * 16;
    int arow = rowBase + m;
    f32x4 acc[8];
#pragma unroll
    for (int i = 0; i < 8; i++) acc[i] = (f32x4){0.f, 0.f, 0.f, 0.f};
    const unsigned short* whi = wfrag;
    const unsigned short* wlo = wfrag + 16384;

#pragma unroll
    for (int kit = 0; kit < 4; kit++) {
        float a[8];
        if (arow < M) {
            const float4* ap = (const float4*)(A + (size_t)arow * 128 + kit * 32 + quad * 8);
            float4 f0 = ap[0], f1 = ap[1];
            a[0] = f0.x; a[1] = f0.y; a[2] = f0.z; a[3] = f0.w;
            a[4] = f1.x; a[5] = f1.y; a[6] = f1.z; a[7] = f1.w;
        } else {
#pragma unroll
            for (int j = 0; j < 8; j++) a[j] = 0.f;
        }
        short8 ahi, alo;
#pragma unroll
        for (int j = 0; j < 8; j++) {
            unsigned short h = f2bf(a[j]);
            ahi[j] = (short)h;
            alo[j] = (short)f2bf(a[j] - bf2f(h));
        }
        int fb = kit * 4096 + lane * 8;
#pragma unroll
        for (int nt = 0; nt < 8; nt++) {
            int idx = fb + nt * 512;
            short8 bhi = *(const short8*)(whi + idx);
            short8 blo = *(const short8*)(wlo + idx);
            acc[nt] = __builtin_amdgcn_mfma_f32_16x16x32_bf16(ahi, bhi, acc[nt], 0, 0, 0);
            acc[nt] = __builtin_amdgcn_mfma_f32_16x16x32_bf16(alo, bhi, acc[nt], 0, 0, 0);
            acc[nt] = __builtin_amdgcn_mfma_f32_16x16x32_bf16(ahi, blo, acc[nt], 0, 0, 0);
        }
    }
    // scale by dinv; C layout: col = nt*16 + (lane&15), row = quad*4 + reg
    float dv = (arow < M) ? dinv[arow] : 0.f;
    float s0 = __shfl(dv, quad * 4 + 0), s1 = __shfl(dv, quad * 4 + 1);
    float s2 = __shfl(dv, quad * 4 + 2), s3 = __shfl(dv, quad * 4 + 3);
    unsigned short* ws = scr + wave * 16 * 136;
#pragma unroll
    for (int nt = 0; nt < 8; nt++) {
        ws[(quad * 4 + 0) * 136 + nt * 16 + m] = f2bf(acc[nt][0] * s0);
        ws[(quad * 4 + 1) * 136 + nt * 16 + m] = f2bf(acc[nt][1] * s1);
        ws[(quad * 4 + 2) * 136 + nt * 16 + m] = f2bf(acc[nt][2] * s2);
        ws[(quad * 4 + 3) * 136 + nt * 16 + m] = f2bf(acc[nt][3] * s3);
    }
    __syncthreads();
#pragma unroll
    for (int i = 0; i < 4; i++) {
        int rl = i * 4 + quad;
        int grow = rowBase + rl;
        if (grow < M) {
            short8 v = *(const short8*)(ws + rl * 136 + m * 8);
            *(short8*)(ybf + (size_t)grow * 128 + m * 8) = v;
        }
    }
}

// ---------------- CSR aggregation (bf16 gather, wave-per-node, 8-deep MLP) ----------------

__global__ __launch_bounds__(256) void k_agg(
    const unsigned short* __restrict__ y, const float* __restrict__ dinv,
    const int* __restrict__ rp, const int* __restrict__ esrc,
    const float* __restrict__ bias, float* __restrict__ out, int relu, int N) {
    int wave = threadIdx.x >> 6;
    int lane = threadIdx.x & 63;
    int node = blockIdx.x * 4 + wave;
    if (node >= N) return;
    const unsigned* y2 = (const unsigned*)y;   // 2 bf16 per u32, row stride 64
    unsigned vs = y2[(size_t)node * 64 + lane];       // self loop
    float a0 = bf2f(vs & 0xFFFF), a1 = bf2f(vs >> 16);
    int beg = rp[node], end = rp[node + 1];
    int j = beg;
    for (; j + 8 <= end; j += 8) {
        int s0 = esrc[j], s1 = esrc[j + 1], s2 = esrc[j + 2], s3 = esrc[j + 3];
        int s4 = esrc[j + 4], s5 = esrc[j + 5], s6 = esrc[j + 6], s7 = esrc[j + 7];
        unsigned v0 = y2[(size_t)s0 * 64 + lane];
        unsigned v1 = y2[(size_t)s1 * 64 + lane];
        unsigned v2 = y2[(size_t)s2 * 64 + lane];
        unsigned v3 = y2[(size_t)s3 * 64 + lane];
        unsigned v4 = y2[(size_t)s4 * 64 + lane];
        unsigned v5 = y2[(size_t)s5 * 64 + lane];
        unsigned v6 = y2[(size_t)s6 * 64 + lane];
        unsigned v7 = y2[(size_t)s7 * 64 + lane];
        a0 += bf2f(v0 & 0xFFFF); a1 += bf2f(v0 >> 16);
        a0 += bf2f(v1 & 0xFFFF); a1 += bf2f(v1 >> 16);
        a0 += bf2f(v2 & 0xFFFF); a1 += bf2f(v2 >> 16);
        a0 += bf2f(v3 & 0xFFFF); a1 += bf2f(v3 >> 16);
        a0 += bf2f(v4 & 0xFFFF); a1 += bf2f(v4 >> 16);
        a0 += bf2f(v5 & 0xFFFF); a1 += bf2f(v5 >> 16);
        a0 += bf2f(v6 & 0xFFFF); a1 += bf2f(v6 >> 16);
        a0 += bf2f(v7 & 0xFFFF); a1 += bf2f(v7 >> 16);
    }
    for (; j < end; j++) {
        unsigned v = y2[(size_t)esrc[j] * 64 + lane];
        a0 += bf2f(v & 0xFFFF); a1 += bf2f(v >> 16);
    }
    float s = dinv[node];
    float2 bv = ((const float2*)bias)[lane];
    float o0 = s * a0 + bv.x;
    float o1 = s * a1 + bv.y;
    if (relu) { o0 = fmaxf(o0, 0.f); o1 = fmaxf(o1, 0.f); }
    ((float2*)out)[(size_t)node * 64 + lane] = make_float2(o0, o1);
}

// ---------------- mean pool (batch sorted -> binary search boundaries) ----------------

__global__ __launch_bounds__(128) void k_pool(
    const float* __restrict__ h, const int* __restrict__ batch,
    float* __restrict__ g, int n) {
    int gid = blockIdx.x;
    int f = threadIdx.x;
    int lo = 0, hi = n;
    while (lo < hi) { int mid = (lo + hi) >> 1; if (batch[mid] < gid) lo = mid + 1; else hi = mid; }
    int start = lo;
    hi = n;
    while (lo < hi) { int mid = (lo + hi) >> 1; if (batch[mid] < gid + 1) lo = mid + 1; else hi = mid; }
    int end = lo;
    float acc = 0.f;
    for (int i = start; i < end; i++) acc += h[(size_t)i * DIM + f];
    int cnt = end - start;
    g[gid * DIM + f] = acc / (float)(cnt > 0 ? cnt : 1);
}

// ---------------- classifier head: out = g @ Wc + bc ----------------

__global__ __launch_bounds__(128) void k_final(
    const float* __restrict__ g, const float* __restrict__ Wc,
    const float* __restrict__ bc, float* __restrict__ out) {
    __shared__ float row[DIM];
    int gid = blockIdx.x;
    row[threadIdx.x] = g[gid * DIM + threadIdx.x];
    __syncthreads();
    int c = threadIdx.x;
    if (c < NCLS) {
        float acc = bc[c];
#pragma unroll 16
        for (int k = 0; k < DIM; k++) acc += row[k] * Wc[k * NCLS + c];
        out[gid * NCLS + c] = acc;
    }
}

extern "C" void kernel_launch(void* const* d_in, const int* in_sizes, int n_in,
                              void* d_out, int out_size, void* d_ws, size_t ws_size,
                              hipStream_t stream) {
    const float* x    = (const float*)d_in[0];
    const int*   ei   = (const int*)d_in[1];
    const int*   batch= (const int*)d_in[2];
    const float* W1   = (const float*)d_in[3];
    const float* b1   = (const float*)d_in[4];
    const float* W2   = (const float*)d_in[5];
    const float* b2   = (const float*)d_in[6];
    const float* Wc   = (const float*)d_in[7];
    const float* bc   = (const float*)d_in[8];
    float* out = (float*)d_out;
    const int N = N_NODES, E = N_EDGES;
    const int* src = ei;
    const int* dst = ei + E;

    char* ws = (char*)d_ws;
    size_t off = 0;
    auto carve = [&](size_t bytes) -> void* {
        void* p = ws + off;
        off = (off + bytes + 255) & ~(size_t)255;
        return p;
    };
    int*      deg      = (int*)     carve((size_t)N * 4);
    int*      rp       = (int*)     carve((size_t)(N + 1) * 4);
    int*      partials = (int*)     carve(64 * 4);
    float*    dinv     = (float*)   carve((size_t)N * 4);
    int*      bcur     = (int*)     carve(NBKT * 4);
    unsigned* bpack    = (unsigned*)carve((size_t)E * 4);
    int*      esrc     = (int*)     carve((size_t)E * 4);
    unsigned short* wf1 = (unsigned short*)carve(2 * 16384 * 2);
    unsigned short* wf2 = (unsigned short*)carve(2 * 16384 * 2);
    unsigned short* bufY = (unsigned short*)carve((size_t)N * DIM * 2);
    float*    bufH     = (float*)   carve((size_t)N * DIM * 4);
    float*    g        = (float*)   carve((size_t)N_GRAPHS * DIM * 4);
    (void)ws_size; (void)n_in; (void)in_sizes; (void)out_size;

    int nb = (N + 2047) / 2048;  // 49
    hipLaunchKernelGGL(k_init,   dim3((N + 255) / 256), dim3(256), 0, stream, deg, N);
    hipLaunchKernelGGL(k_hist,   dim3((E + 255) / 256), dim3(256), 0, stream, dst, deg, E);
    hipLaunchKernelGGL(k_wprep,  dim3(64), dim3(256), 0, stream, W1, wf1);
    hipLaunchKernelGGL(k_wprep,  dim3(64), dim3(256), 0, stream, W2, wf2);
    hipLaunchKernelGGL(k_scan1,  dim3(nb), dim3(256), 0, stream, deg, rp, partials, dinv, N);
    hipLaunchKernelGGL(k_scan2,  dim3(1),  dim3(64),  0, stream, partials, nb, rp, N);
    hipLaunchKernelGGL(k_scan3,  dim3(nb), dim3(256), 0, stream, rp, partials, bcur, N);
    hipLaunchKernelGGL(k_bucket, dim3((E + 4095) / 4096), dim3(256), 0, stream, src, dst, bcur, bpack, E);
    hipLaunchKernelGGL(k_bsort,  dim3(NBKT), dim3(256), 0, stream, bpack, rp, esrc, N);

    int gemmGrid = (N + 63) / 64;  // 1563
    // conv1: y = bf16(dinv*(x@W1)); h = relu(dinv*agg(y) + b1)
    hipLaunchKernelGGL(k_gemm_mfma, dim3(gemmGrid), dim3(256), 0, stream, x, wf1, dinv, bufY, N);
    hipLaunchKernelGGL(k_agg, dim3((N + 3) / 4), dim3(256), 0, stream, bufY, dinv, rp, esrc, b1, bufH, 1, N);
    // conv2
    hipLaunchKernelGGL(k_gemm_mfma, dim3(gemmGrid), dim3(256), 0, stream, bufH, wf2, dinv, bufY, N);
    hipLaunchKernelGGL(k_agg, dim3((N + 3) / 4), dim3(256), 0, stream, bufY, dinv, rp, esrc, b2, bufH, 0, N);
    // pool + head
    hipLaunchKernelGGL(k_pool,  dim3(N_GRAPHS), dim3(128), 0, stream, bufH, batch, g, N);
    hipLaunchKernelGGL(k_final, dim3(N_GRAPHS), dim3(128), 0, stream, g, Wc, bc, out);
}

// Round 4
// 377.350 us; speedup vs baseline: 1.8106x; 1.3767x over previous
//
#include <hip/hip_runtime.h>

#define N_NODES 100000
#define N_EDGES 1600000
#define N_GRAPHS 512
#define DIM 128
#define NCLS 10
#define NBKT 782          // buckets of 128 dst nodes: 782*128 = 100096 >= N
#define BCAP 2560         // padded bucket region (mean 2048, sigma~45 -> 11 sigma slack)

typedef __attribute__((ext_vector_type(8))) short short8;
typedef __attribute__((ext_vector_type(4))) float f32x4;

static __device__ __forceinline__ unsigned short f2bf(float f) {
    unsigned u = __float_as_uint(f);
    unsigned r = (u + 0x7FFF + ((u >> 16) & 1)) >> 16;  // RNE
    return (unsigned short)r;
}
static __device__ __forceinline__ float bf2f(unsigned u) {
    return __uint_as_float(u << 16);
}

// ---------------- edge prep (single-pass padded bucketing; no global histogram) ----------------

__global__ void k_zero(int* __restrict__ bcnt) {
    int i = blockIdx.x * 256 + threadIdx.x;
    if (i < NBKT) bcnt[i] = 0;
}

// Partition edges into 782 buckets of 128 dst-nodes, packed (dstlocal<<17 | src),
// appended into fixed regions bpack[b*BCAP ...]. Block-local LDS histogram ->
// one global atomic per touched bucket per block -> dense-ish appends.
__global__ __launch_bounds__(256) void k_bucket(
    const int* __restrict__ src, const int* __restrict__ dst,
    int* __restrict__ bcnt, unsigned* __restrict__ bpack, int E) {
    __shared__ int cnt[NBKT];
    __shared__ int base[NBKT];
    int tid = threadIdx.x;
    for (int i = tid; i < NBKT; i += 256) cnt[i] = 0;
    __syncthreads();
    int e0 = blockIdx.x * 4096 + tid;
    unsigned pk[16]; short bk[16];
#pragma unroll
    for (int j = 0; j < 16; j++) {
        int e = e0 + j * 256;
        if (e < E) {
            int s = src[e], d = dst[e];
            bk[j] = (short)(d >> 7);
            pk[j] = ((unsigned)(d & 127) << 17) | (unsigned)s;
            atomicAdd(&cnt[bk[j]], 1);
        } else bk[j] = -1;
    }
    __syncthreads();
    for (int i = tid; i < NBKT; i += 256) {
        int c = cnt[i];
        base[i] = c ? atomicAdd(&bcnt[i], c) : 0;
        cnt[i] = 0;
    }
    __syncthreads();
#pragma unroll
    for (int j = 0; j < 16; j++) {
        if (bk[j] >= 0) {
            int p = base[bk[j]] + atomicAdd(&cnt[bk[j]], 1);
            if (p < BCAP) bpack[(size_t)bk[j] * BCAP + p] = pk[j];
        }
    }
}

// Exclusive prefix over the 782 bucket counts -> global CSR base per bucket.
__global__ __launch_bounds__(256) void k_bscan(const int* __restrict__ bcnt,
                                               int* __restrict__ bbase) {
    __shared__ int lds[256];
    int tid = threadIdx.x;
    int v[4], pre[4];
    int s = 0;
#pragma unroll
    for (int j = 0; j < 4; j++) {
        int idx = tid * 4 + j;
        v[j] = (idx < NBKT) ? min(bcnt[idx], BCAP) : 0;
        pre[j] = s; s += v[j];
    }
    lds[tid] = s;
    __syncthreads();
    for (int off = 1; off < 256; off <<= 1) {
        int t = (tid >= off) ? lds[tid - off] : 0;
        __syncthreads();
        lds[tid] += t;
        __syncthreads();
    }
    int excl = lds[tid] - s;
#pragma unroll
    for (int j = 0; j < 4; j++) {
        int idx = tid * 4 + j;
        if (idx < NBKT) bbase[idx] = excl + pre[j];
    }
}

// Per bucket: LDS degree count -> LDS scan -> emit rp/dinv -> scatter edges to final CSR slot.
__global__ __launch_bounds__(256) void k_bsort(
    const unsigned* __restrict__ bpack, const int* __restrict__ bcnt,
    const int* __restrict__ bbase, int* __restrict__ rp, float* __restrict__ dinv,
    int* __restrict__ esrc, int N) {
    __shared__ int cnt[128];
    __shared__ int scan[128];
    __shared__ int cur[128];
    int b = blockIdx.x, tid = threadIdx.x;
    int n0 = b << 7;
    int m = min(bcnt[b], BCAP);
    int gbase = bbase[b];
    const unsigned* bp = bpack + (size_t)b * BCAP;
    if (tid < 128) cnt[tid] = 0;
    __syncthreads();
    for (int j = tid; j < m; j += 256) atomicAdd(&cnt[bp[j] >> 17], 1);
    __syncthreads();
    if (tid < 128) scan[tid] = cnt[tid];
    __syncthreads();
    for (int off = 1; off < 128; off <<= 1) {
        int t = (tid < 128 && tid >= off) ? scan[tid - off] : 0;
        __syncthreads();
        if (tid < 128) scan[tid] += t;
        __syncthreads();
    }
    if (tid < 128) {
        int c = cnt[tid];
        int excl = scan[tid] - c;
        int node = n0 + tid;
        if (node <= N) rp[node] = gbase + excl;
        if (node < N) dinv[node] = rsqrtf((float)(c + 1));  // +1 self loop
        cur[tid] = gbase + excl;
    }
    __syncthreads();
    for (int j = tid; j < m; j += 256) {
        unsigned pk = bp[j];
        int p = atomicAdd(&cur[pk >> 17], 1);
        esrc[p] = (int)(pk & 0x1FFFF);
    }
}

// ---------------- W fragment prep: W [128][128] fp32 -> MFMA B-layout bf16 hi/lo ----------------
// wfrag[hi: t<16384][lo: +16384], t = ((kit*8+nt)*64+lane)*8+j
// B element: k = kit*32 + (lane>>4)*8 + j, n = nt*16 + (lane&15)

__global__ void k_wprep(const float* __restrict__ W, unsigned short* __restrict__ wfrag) {
    int t = blockIdx.x * 256 + threadIdx.x;   // 0..16383
    int j = t & 7, lane = (t >> 3) & 63, nt = (t >> 9) & 7, kit = t >> 12;
    int k = kit * 32 + (lane >> 4) * 8 + j;
    int n = nt * 16 + (lane & 15);
    float v = W[k * 128 + n];
    unsigned short h = f2bf(v);
    wfrag[t] = h;
    wfrag[16384 + t] = f2bf(v - bf2f(h));
}

// ---------------- MFMA GEMM (fp32 A): ybf = bf16(dinv * (A @ W)) ----------------
// fp32-accurate hi/lo split: A@W = Ahi@Whi + Ahi@Wlo + Alo@Whi.
// 256 thr = 4 waves; wave strip = 32 rows x 128 cols (two 16-row sets share B frags).

__global__ __launch_bounds__(256) void k_gemm_f32(
    const float* __restrict__ A, const unsigned short* __restrict__ wfrag,
    const float* __restrict__ dinv, unsigned short* __restrict__ ybf, int M) {
    __shared__ unsigned short scr[4 * 32 * 136];
    int tid = threadIdx.x, wave = tid >> 6, lane = tid & 63;
    int m = lane & 15, quad = lane >> 4;
    int rowBase = blockIdx.x * 128 + wave * 32;
    int r0 = rowBase + m, r1 = rowBase + 16 + m;
    f32x4 acc0[8], acc1[8];
#pragma unroll
    for (int i = 0; i < 8; i++) { acc0[i] = (f32x4){0,0,0,0}; acc1[i] = (f32x4){0,0,0,0}; }
    const unsigned short* whi = wfrag;
    const unsigned short* wlo = wfrag + 16384;

#pragma unroll
    for (int kit = 0; kit < 4; kit++) {
        float a0[8], a1[8];
        if (r0 < M) {
            const float4* ap = (const float4*)(A + (size_t)r0 * 128 + kit * 32 + quad * 8);
            float4 f0 = ap[0], f1 = ap[1];
            a0[0]=f0.x; a0[1]=f0.y; a0[2]=f0.z; a0[3]=f0.w; a0[4]=f1.x; a0[5]=f1.y; a0[6]=f1.z; a0[7]=f1.w;
        } else { for (int j = 0; j < 8; j++) a0[j] = 0.f; }
        if (r1 < M) {
            const float4* ap = (const float4*)(A + (size_t)r1 * 128 + kit * 32 + quad * 8);
            float4 f0 = ap[0], f1 = ap[1];
            a1[0]=f0.x; a1[1]=f0.y; a1[2]=f0.z; a1[3]=f0.w; a1[4]=f1.x; a1[5]=f1.y; a1[6]=f1.z; a1[7]=f1.w;
        } else { for (int j = 0; j < 8; j++) a1[j] = 0.f; }
        short8 ahi0, alo0, ahi1, alo1;
#pragma unroll
        for (int j = 0; j < 8; j++) {
            unsigned short h0 = f2bf(a0[j]);
            ahi0[j] = (short)h0; alo0[j] = (short)f2bf(a0[j] - bf2f(h0));
            unsigned short h1 = f2bf(a1[j]);
            ahi1[j] = (short)h1; alo1[j] = (short)f2bf(a1[j] - bf2f(h1));
        }
        int fb = kit * 4096 + lane * 8;
#pragma unroll
        for (int nt = 0; nt < 8; nt++) {
            int idx = fb + nt * 512;
            short8 bhi = *(const short8*)(whi + idx);
            short8 blo = *(const short8*)(wlo + idx);
            acc0[nt] = __builtin_amdgcn_mfma_f32_16x16x32_bf16(ahi0, bhi, acc0[nt], 0, 0, 0);
            acc0[nt] = __builtin_amdgcn_mfma_f32_16x16x32_bf16(alo0, bhi, acc0[nt], 0, 0, 0);
            acc0[nt] = __builtin_amdgcn_mfma_f32_16x16x32_bf16(ahi0, blo, acc0[nt], 0, 0, 0);
            acc1[nt] = __builtin_amdgcn_mfma_f32_16x16x32_bf16(ahi1, bhi, acc1[nt], 0, 0, 0);
            acc1[nt] = __builtin_amdgcn_mfma_f32_16x16x32_bf16(alo1, bhi, acc1[nt], 0, 0, 0);
            acc1[nt] = __builtin_amdgcn_mfma_f32_16x16x32_bf16(ahi1, blo, acc1[nt], 0, 0, 0);
        }
    }
    // C layout: col = nt*16 + m, row(in tile) = quad*4 + reg; set0 rows +0, set1 rows +16
    float dv0 = (r0 < M) ? dinv[r0] : 0.f;
    float dv1 = (r1 < M) ? dinv[r1] : 0.f;
    unsigned short* wsm = scr + wave * 32 * 136;
#pragma unroll
    for (int rg = 0; rg < 4; rg++) {
        float s0 = __shfl(dv0, quad * 4 + rg);
        float s1 = __shfl(dv1, quad * 4 + rg);
#pragma unroll
        for (int nt = 0; nt < 8; nt++) {
            wsm[(quad * 4 + rg) * 136 + nt * 16 + m] = f2bf(acc0[nt][rg] * s0);
            wsm[(16 + quad * 4 + rg) * 136 + nt * 16 + m] = f2bf(acc1[nt][rg] * s1);
        }
    }
    __syncthreads();
#pragma unroll
    for (int i = 0; i < 8; i++) {
        int rl = i * 4 + quad;
        int grow = rowBase + rl;
        if (grow < M) {
            short8 v = *(const short8*)(wsm + rl * 136 + m * 8);
            *(short8*)(ybf + (size_t)grow * 128 + m * 8) = v;
        }
    }
}

// ---------------- MFMA GEMM (bf16 A, exact): ybf = bf16(dinv * (A @ W)) ----------------
// A is already bf16 -> A@W = A@Whi + A@Wlo (2 MFMA per tile, half the A traffic).

__global__ __launch_bounds__(256) void k_gemm_bf(
    const unsigned short* __restrict__ A, const unsigned short* __restrict__ wfrag,
    const float* __restrict__ dinv, unsigned short* __restrict__ ybf, int M) {
    __shared__ unsigned short scr[4 * 32 * 136];
    int tid = threadIdx.x, wave = tid >> 6, lane = tid & 63;
    int m = lane & 15, quad = lane >> 4;
    int rowBase = blockIdx.x * 128 + wave * 32;
    int r0 = rowBase + m, r1 = rowBase + 16 + m;
    f32x4 acc0[8], acc1[8];
#pragma unroll
    for (int i = 0; i < 8; i++) { acc0[i] = (f32x4){0,0,0,0}; acc1[i] = (f32x4){0,0,0,0}; }
    const unsigned short* whi = wfrag;
    const unsigned short* wlo = wfrag + 16384;

#pragma unroll
    for (int kit = 0; kit < 4; kit++) {
        short8 ah0, ah1;
        if (r0 < M) ah0 = *(const short8*)(A + (size_t)r0 * 128 + kit * 32 + quad * 8);
        else { for (int j = 0; j < 8; j++) ah0[j] = 0; }
        if (r1 < M) ah1 = *(const short8*)(A + (size_t)r1 * 128 + kit * 32 + quad * 8);
        else { for (int j = 0; j < 8; j++) ah1[j] = 0; }
        int fb = kit * 4096 + lane * 8;
#pragma unroll
        for (int nt = 0; nt < 8; nt++) {
            int idx = fb + nt * 512;
            short8 bhi = *(const short8*)(whi + idx);
            short8 blo = *(const short8*)(wlo + idx);
            acc0[nt] = __builtin_amdgcn_mfma_f32_16x16x32_bf16(ah0, bhi, acc0[nt], 0, 0, 0);
            acc0[nt] = __builtin_amdgcn_mfma_f32_16x16x32_bf16(ah0, blo, acc0[nt], 0, 0, 0);
            acc1[nt] = __builtin_amdgcn_mfma_f32_16x16x32_bf16(ah1, bhi, acc1[nt], 0, 0, 0);
            acc1[nt] = __builtin_amdgcn_mfma_f32_16x16x32_bf16(ah1, blo, acc1[nt], 0, 0, 0);
        }
    }
    float dv0 = (r0 < M) ? dinv[r0] : 0.f;
    float dv1 = (r1 < M) ? dinv[r1] : 0.f;
    unsigned short* wsm = scr + wave * 32 * 136;
#pragma unroll
    for (int rg = 0; rg < 4; rg++) {
        float s0 = __shfl(dv0, quad * 4 + rg);
        float s1 = __shfl(dv1, quad * 4 + rg);
#pragma unroll
        for (int nt = 0; nt < 8; nt++) {
            wsm[(quad * 4 + rg) * 136 + nt * 16 + m] = f2bf(acc0[nt][rg] * s0);
            wsm[(16 + quad * 4 + rg) * 136 + nt * 16 + m] = f2bf(acc1[nt][rg] * s1);
        }
    }
    __syncthreads();
#pragma unroll
    for (int i = 0; i < 8; i++) {
        int rl = i * 4 + quad;
        int grow = rowBase + rl;
        if (grow < M) {
            short8 v = *(const short8*)(wsm + rl * 136 + m * 8);
            *(short8*)(ybf + (size_t)grow * 128 + m * 8) = v;
        }
    }
}

// ---------------- CSR aggregation (bf16 gather, wave-per-node) -> bf16 out ----------------

__global__ __launch_bounds__(256) void k_agg(
    const unsigned short* __restrict__ y, const float* __restrict__ dinv,
    const int* __restrict__ rp, const int* __restrict__ esrc,
    const float* __restrict__ bias, unsigned* __restrict__ out, int relu, int N) {
    int wave = threadIdx.x >> 6;
    int lane = threadIdx.x & 63;
    int node = blockIdx.x * 4 + wave;
    if (node >= N) return;
    const unsigned* y2 = (const unsigned*)y;   // 2 bf16 per u32, row stride 64
    unsigned vs = y2[(size_t)node * 64 + lane];       // self loop
    float a0 = bf2f(vs & 0xFFFF), a1 = bf2f(vs >> 16);
    int beg = rp[node], end = rp[node + 1];
    int j = beg;
    for (; j + 8 <= end; j += 8) {
        int s0 = esrc[j], s1 = esrc[j + 1], s2 = esrc[j + 2], s3 = esrc[j + 3];
        int s4 = esrc[j + 4], s5 = esrc[j + 5], s6 = esrc[j + 6], s7 = esrc[j + 7];
        unsigned v0 = y2[(size_t)s0 * 64 + lane];
        unsigned v1 = y2[(size_t)s1 * 64 + lane];
        unsigned v2 = y2[(size_t)s2 * 64 + lane];
        unsigned v3 = y2[(size_t)s3 * 64 + lane];
        unsigned v4 = y2[(size_t)s4 * 64 + lane];
        unsigned v5 = y2[(size_t)s5 * 64 + lane];
        unsigned v6 = y2[(size_t)s6 * 64 + lane];
        unsigned v7 = y2[(size_t)s7 * 64 + lane];
        a0 += bf2f(v0 & 0xFFFF); a1 += bf2f(v0 >> 16);
        a0 += bf2f(v1 & 0xFFFF); a1 += bf2f(v1 >> 16);
        a0 += bf2f(v2 & 0xFFFF); a1 += bf2f(v2 >> 16);
        a0 += bf2f(v3 & 0xFFFF); a1 += bf2f(v3 >> 16);
        a0 += bf2f(v4 & 0xFFFF); a1 += bf2f(v4 >> 16);
        a0 += bf2f(v5 & 0xFFFF); a1 += bf2f(v5 >> 16);
        a0 += bf2f(v6 & 0xFFFF); a1 += bf2f(v6 >> 16);
        a0 += bf2f(v7 & 0xFFFF); a1 += bf2f(v7 >> 16);
    }
    for (; j < end; j++) {
        unsigned v = y2[(size_t)esrc[j] * 64 + lane];
        a0 += bf2f(v & 0xFFFF); a1 += bf2f(v >> 16);
    }
    float s = dinv[node];
    float2 bv = ((const float2*)bias)[lane];
    float o0 = s * a0 + bv.x;
    float o1 = s * a1 + bv.y;
    if (relu) { o0 = fmaxf(o0, 0.f); o1 = fmaxf(o1, 0.f); }
    out[(size_t)node * 64 + lane] = (unsigned)f2bf(o0) | ((unsigned)f2bf(o1) << 16);
}

// ---------------- mean pool (bf16 h in, sorted batch, 4-wave partials) ----------------

__global__ __launch_bounds__(256) void k_pool(
    const unsigned* __restrict__ h2, const int* __restrict__ batch,
    float* __restrict__ g, int n) {
    __shared__ float2 red[4][64];
    int gid = blockIdx.x;
    int tid = threadIdx.x, wave = tid >> 6, lane = tid & 63;
    int lo = 0, hi = n;
    while (lo < hi) { int mid = (lo + hi) >> 1; if (batch[mid] < gid) lo = mid + 1; else hi = mid; }
    int start = lo;
    hi = n;
    while (lo < hi) { int mid = (lo + hi) >> 1; if (batch[mid] < gid + 1) lo = mid + 1; else hi = mid; }
    int end = lo;
    float a0 = 0.f, a1 = 0.f;
    for (int r = start + wave; r < end; r += 4) {
        unsigned v = h2[(size_t)r * 64 + lane];
        a0 += bf2f(v & 0xFFFF); a1 += bf2f(v >> 16);
    }
    red[wave][lane] = make_float2(a0, a1);
    __syncthreads();
    if (tid < 64) {
        float2 s = red[0][tid];
        s.x += red[1][tid].x; s.y += red[1][tid].y;
        s.x += red[2][tid].x; s.y += red[2][tid].y;
        s.x += red[3][tid].x; s.y += red[3][tid].y;
        int cnt = end - start;
        float inv = 1.f / (float)(cnt > 0 ? cnt : 1);
        ((float2*)g)[gid * 64 + tid] = make_float2(s.x * inv, s.y * inv);
    }
}

// ---------------- classifier head: out = g @ Wc + bc ----------------

__global__ __launch_bounds__(128) void k_final(
    const float* __restrict__ g, const float* __restrict__ Wc,
    const float* __restrict__ bc, float* __restrict__ out) {
    __shared__ float row[DIM];
    int gid = blockIdx.x;
    row[threadIdx.x] = g[gid * DIM + threadIdx.x];
    __syncthreads();
    int c = threadIdx.x;
    if (c < NCLS) {
        float acc = bc[c];
#pragma unroll 16
        for (int k = 0; k < DIM; k++) acc += row[k] * Wc[k * NCLS + c];
        out[gid * NCLS + c] = acc;
    }
}

extern "C" void kernel_launch(void* const* d_in, const int* in_sizes, int n_in,
                              void* d_out, int out_size, void* d_ws, size_t ws_size,
                              hipStream_t stream) {
    const float* x    = (const float*)d_in[0];
    const int*   ei   = (const int*)d_in[1];
    const int*   batch= (const int*)d_in[2];
    const float* W1   = (const float*)d_in[3];
    const float* b1   = (const float*)d_in[4];
    const float* W2   = (const float*)d_in[5];
    const float* b2   = (const float*)d_in[6];
    const float* Wc   = (const float*)d_in[7];
    const float* bc   = (const float*)d_in[8];
    float* out = (float*)d_out;
    const int N = N_NODES, E = N_EDGES;
    const int* src = ei;
    const int* dst = ei + E;

    char* ws = (char*)d_ws;
    size_t off = 0;
    auto carve = [&](size_t bytes) -> void* {
        void* p = ws + off;
        off = (off + bytes + 255) & ~(size_t)255;
        return p;
    };
    int*      rp    = (int*)     carve((size_t)(N + 1) * 4);
    float*    dinv  = (float*)   carve((size_t)N * 4);
    int*      bcnt  = (int*)     carve(NBKT * 4);
    int*      bbase = (int*)     carve(NBKT * 4);
    unsigned* bpack = (unsigned*)carve((size_t)NBKT * BCAP * 4);
    int*      esrc  = (int*)     carve((size_t)E * 4);
    unsigned short* wf1 = (unsigned short*)carve(2 * 16384 * 2);
    unsigned short* wf2 = (unsigned short*)carve(2 * 16384 * 2);
    unsigned short* bufY = (unsigned short*)carve((size_t)N * DIM * 2);
    unsigned short* bufH = (unsigned short*)carve((size_t)N * DIM * 2);
    float*    g     = (float*)   carve((size_t)N_GRAPHS * DIM * 4);
    (void)ws_size; (void)n_in; (void)in_sizes; (void)out_size;

    hipLaunchKernelGGL(k_zero,   dim3((NBKT + 255) / 256), dim3(256), 0, stream, bcnt);
    hipLaunchKernelGGL(k_wprep,  dim3(64), dim3(256), 0, stream, W1, wf1);
    hipLaunchKernelGGL(k_wprep,  dim3(64), dim3(256), 0, stream, W2, wf2);
    hipLaunchKernelGGL(k_bucket, dim3((E + 4095) / 4096), dim3(256), 0, stream, src, dst, bcnt, bpack, E);
    hipLaunchKernelGGL(k_bscan,  dim3(1), dim3(256), 0, stream, bcnt, bbase);
    hipLaunchKernelGGL(k_bsort,  dim3(NBKT), dim3(256), 0, stream, bpack, bcnt, bbase, rp, dinv, esrc, N);

    int gemmGrid = (N + 127) / 128;  // 782
    // conv1: Y1 = bf16(dinv*(x@W1)); H1 = bf16(relu(dinv*agg(Y1) + b1))
    hipLaunchKernelGGL(k_gemm_f32, dim3(gemmGrid), dim3(256), 0, stream, x, wf1, dinv, bufY, N);
    hipLaunchKernelGGL(k_agg, dim3((N + 3) / 4), dim3(256), 0, stream, bufY, dinv, rp, esrc, b1, (unsigned*)bufH, 1, N);
    // conv2: Y2 = bf16(dinv*(H1@W2)); H2 = bf16(dinv*agg(Y2) + b2)
    hipLaunchKernelGGL(k_gemm_bf, dim3(gemmGrid), dim3(256), 0, stream, bufH, wf2, dinv, bufY, N);
    hipLaunchKernelGGL(k_agg, dim3((N + 3) / 4), dim3(256), 0, stream, bufY, dinv, rp, esrc, b2, (unsigned*)bufH, 0, N);
    // pool + head
    hipLaunchKernelGGL(k_pool,  dim3(N_GRAPHS), dim3(256), 0, stream, (const unsigned*)bufH, batch, g, N);
    hipLaunchKernelGGL(k_final, dim3(N_GRAPHS), dim3(128), 0, stream, g, Wc, bc, out);
}